// Round 10
// baseline (224.428 us; speedup 1.0000x reference)
//
#include <hip/hip_runtime.h>

namespace {

constexpr int BATCH = 256;
constexpr int S_IN  = 256;
constexpr int NNEUR = 128;
constexpr int NSYN  = 256;
constexpr int MOUT  = 256;
constexpr int WSTR  = 130;            // padded LDS stride for WrecT rows
constexpr float NO_SPIKE_T = 1.0e30f; // finite sentinel (ref holds inf; inf-inf=nan fails)
constexpr float K1  = 0.72134752044448170f;  // log2(e)/2  : exp(t/2) = 2^(K1*t)
constexpr float NL2 = -1.3862943611198906f;  // -2*ln2     : t = NL2*log2(z)
constexpr float ZEPS = (float)(1.0 - 1e-6);
constexpr float Z20F = 4.5399929762484854e-05f;  // e^-10  (t=20 bound in z-space)

// dynamic LDS layout (bytes)
constexpr int LDS_WREC  = NNEUR * WSTR * 4;        // 66560
constexpr int LDS_EV    = LDS_WREC;                // float4 ev[264]: {sid_bits, z_in, e, e^2}
constexpr int LDS_SPK   = LDS_EV + 264 * 16;       // float2 spk[256]: {t_spk, (float)jn}
constexpr int LDS_LT    = LDS_SPK + 256 * 8;       // lt[256] f32 (sort scratch)
constexpr int LDS_TOTAL = LDS_LT + 1024;           // 73856

__device__ __forceinline__ float hw_exp2(float x) { return __builtin_amdgcn_exp2f(x); }
__device__ __forceinline__ float hw_log2(float x) { return __builtin_amdgcn_logf(x); }
__device__ __forceinline__ float hw_rcp(float x)  { return __builtin_amdgcn_rcpf(x); }
__device__ __forceinline__ float rdl(float x, int l) {
    return __builtin_bit_cast(float, __builtin_amdgcn_readlane(__builtin_bit_cast(int, x), l));
}

__global__ void transpose_wff_kernel(const float* __restrict__ wff,
                                     float* __restrict__ wffT) {
    int i = blockIdx.x * blockDim.x + threadIdx.x;   // 32768 threads
    int s = i >> 7;
    int n = i & (NNEUR - 1);
    wffT[i] = wff[n * NSYN + s];
}

template <int CTRL>
__device__ __forceinline__ int dpp_imax(int v) {
    int t = __builtin_amdgcn_update_dpp(v, v, CTRL, 0xf, 0xf, false);
    return (t > v) ? t : v;
}

// z-space candidate: largest valid root z of A z - B z^2 = 1 in (1e-12, zlim).
// z2 >= z1; t = -2 ln z decreasing in z, so max valid z == min t. Invalid -> 0.
__device__ __forceinline__ float cand_z(float A, float B, float zlim) {
    float disc = __builtin_fmaf(A, A, -4.0f * B);
    float r2B  = hw_rcp(B + B);
    float sq   = __fsqrt_rn(disc);          // nan if disc<0 -> masked below
    float z2 = (A + sq) * r2B;
    float z1 = (A - sq) * r2B;
    bool okd = (disc > 0.0f) & (B > 1e-12f);
    bool v2 = okd & (z2 > 1e-12f) & (z2 < zlim);
    bool v1 = okd & (z1 > 1e-12f) & (z1 < zlim);
    return v2 ? z2 : (v1 ? z1 : 0.0f);
}

__global__ __launch_bounds__(64, 1) void lif_event_kernel(
    const float* __restrict__ in_t,
    const int*   __restrict__ in_sid,
    const float* __restrict__ wff,    // (N,NSYN) original, fallback
    const float* __restrict__ wffT,   // (NSYN,N) transposed, preferred
    const float* __restrict__ wrec,   // (N,N) original; staged->LDS transposed
    int use_t,
    float* __restrict__ out_t,
    float* __restrict__ out_id)
{
    extern __shared__ char smem[];
    float*  wrecL = (float*)smem;                 // [j*WSTR + n] = wrec[n][j]
    float4* evL   = (float4*)(smem + LDS_EV);
    float2* spkL  = (float2*)(smem + LDS_SPK);
    float*  lt    = (float*)(smem + LDS_LT);

    const int b = blockIdx.x;
    const int lane = threadIdx.x;

    // ---- stage WrecT into LDS ----
    const float4* wrec4 = (const float4*)wrec;
    for (int i = lane; i < NNEUR * NNEUR / 4; i += 64) {
        float4 v = wrec4[i];
        int n  = i >> 5;
        int c0 = (i & 31) * 4;
        wrecL[(c0 + 0) * WSTR + n] = v.x;
        wrecL[(c0 + 1) * WSTR + n] = v.y;
        wrecL[(c0 + 2) * WSTR + n] = v.z;
        wrecL[(c0 + 3) * WSTR + n] = v.w;
    }

    // ---- load events; stable rank sort; precompute per-event exponentials ----
    float myt[4]; int mys[4];
    for (int q = 0; q < 4; ++q) {
        int k = lane + 64 * q;
        myt[q] = in_t[b * S_IN + k];
        mys[q] = in_sid[b * S_IN + k];
        lt[k] = myt[q];
    }
    __syncthreads();
    int rk[4] = {0, 0, 0, 0};
    for (int j = 0; j < S_IN; ++j) {
        float tj = lt[j];
        #pragma unroll
        for (int q = 0; q < 4; ++q)
            rk[q] += (tj < myt[q] || (tj == myt[q] && j < lane + 64 * q)) ? 1 : 0;
    }
    for (int q = 0; q < 4; ++q) {
        float t = myt[q];
        float zi = hw_exp2(-K1 * t);    // z_in = exp(-t/2)
        float e  = hw_exp2(K1 * t);     // exp(t/2)
        evL[rk[q]] = make_float4(__builtin_bit_cast(float, mys[q]), zi, e, e * e);
    }
    if (lane < 8) evL[S_IN + lane] = make_float4(0.0f, 0.0f, 1.0f, 1.0f);  // pad: t=inf -> z=0
    __syncthreads();

    const int n0 = lane * 2;
    const int n1 = n0 + 1;

    float A0 = 0.f, A1 = 0.f, B0 = 0.f, B1 = 0.f;
    int ptr = 0, cnt = 0;
    float zlim = ZEPS;   // z_cur = 1

    // ---- event slots A..D (depth 4); weights prefetched per slot;
    //      sPre = sid for the NEXT slot-D refill (read one iter ahead) ----
    float4 evA = evL[0], evB = evL[1], evC = evL[2], evD = evL[3];
    float2 wA, wB, wC, wD;
    {
        int s0 = __builtin_bit_cast(int, evA.x);
        int s1 = __builtin_bit_cast(int, evB.x);
        int s2 = __builtin_bit_cast(int, evC.x);
        int s3 = __builtin_bit_cast(int, evD.x);
        if (use_t) {
            wA = *(const float2*)&wffT[s0 * NNEUR + n0];
            wB = *(const float2*)&wffT[s1 * NNEUR + n0];
            wC = *(const float2*)&wffT[s2 * NNEUR + n0];
            wD = *(const float2*)&wffT[s3 * NNEUR + n0];
        } else {
            wA = make_float2(wff[n0 * NSYN + s0], wff[n1 * NSYN + s0]);
            wB = make_float2(wff[n0 * NSYN + s1], wff[n1 * NSYN + s1]);
            wC = make_float2(wff[n0 * NSYN + s2], wff[n1 * NSYN + s2]);
            wD = make_float2(wff[n0 * NSYN + s3], wff[n1 * NSYN + s3]);
        }
    }
    int sPre = __builtin_bit_cast(int, evL[4].x);

    for (int it = 0; it < S_IN + MOUT; ++it) {
        // per-pair candidates in z-space (chain head)
        const float zb0 = cand_z(A0, B0, zlim);
        const float zb1 = cand_z(A1, B1, zlim);
        const float zc = fmaxf(zb0, zb1);
        const int idxl = (zb1 > zb0) ? n1 : n0;   // ties -> n0 (first-min in t)

        // packed key: truncated z (top 25 bits) | (127 - idx) for first-min tiebreak.
        // single speculative DPP imax chain resolves winner AND its index.
        int key = (__builtin_bit_cast(int, zc) & ~127) | (127 - idxl);
        key = dpp_imax<0x111>(key);   // row_shr:1
        key = dpp_imax<0x112>(key);   // row_shr:2
        key = dpp_imax<0x114>(key);   // row_shr:4
        key = dpp_imax<0x118>(key);   // row_shr:8
        key = dpp_imax<0x142>(key);   // row_bcast:15
        key = dpp_imax<0x143>(key);   // row_bcast:31

        // cheap emit decision: any lane crossing before next input event?
        // (max z automatically belongs to a crossing lane when any lane crosses)
        const bool cross = (zc > evA.y) & (zc > Z20F);
        const unsigned long long m = __ballot(cross);

        if (m != 0ull && cnt < MOUT) {
            const int key63 = __builtin_amdgcn_readlane(key, 63);
            const int jn = 127 - (key63 & 127);
            const float zmax = rdl(zc, jn >> 1);          // winner's exact z
            const float2 wr = *(const float2*)&wrecL[jn * WSTR + n0];
            const float em = hw_rcp(zmax);                // exp(t_spk/2) = 1/z
            const float es = em * em;                     // exp(t_spk)
            const float r0 = (n0 == jn) ? 1.0f : 0.0f;
            const float r1 = (n1 == jn) ? 1.0f : 0.0f;
            A0 = __builtin_fmaf(wr.x - r0, em, A0);
            A1 = __builtin_fmaf(wr.y - r1, em, A1);
            B0 = __builtin_fmaf(wr.x, es, B0);
            B1 = __builtin_fmaf(wr.y, es, B1);
            zlim = ZEPS * zmax;
            if (lane == 0)                                 // LDS only; no global store in loop
                spkL[cnt] = make_float2(NL2 * hw_log2(zmax), (float)jn);
            ++cnt;
        } else {
            if (ptr >= S_IN) break;               // no event, no spike: frozen
            const float e  = evA.z;
            const float es = evA.w;
            A0 = __builtin_fmaf(wA.x, e, A0);
            A1 = __builtin_fmaf(wA.y, e, A1);
            B0 = __builtin_fmaf(wA.x, es, B0);
            B1 = __builtin_fmaf(wA.y, es, B1);
            zlim = ZEPS * evA.y;
            ++ptr;
            // shift pipeline
            evA = evB; evB = evC; evC = evD;
            wA = wB; wB = wC; wC = wD;
            // refill slot D: weight load address (sPre) was read LAST consume -> no wait
            if (use_t) {
                wD = *(const float2*)&wffT[sPre * NNEUR + n0];
            } else {
                wD = make_float2(wff[n0 * NSYN + sPre], wff[n1 * NSYN + sPre]);
            }
            evD = evL[ptr + 3];                            // 1-iter slack
            sPre = __builtin_bit_cast(int, evL[ptr + 4].x); // 1-iter slack
        }
    }

    // ---- flush spikes + fills from LDS to global (coalesced, once) ----
    __syncthreads();
    for (int k = lane; k < MOUT; k += 64) {
        float2 s = spkL[k];
        bool live = (k < cnt);
        out_t[b * MOUT + k]  = live ? s.x : NO_SPIKE_T;
        out_id[b * MOUT + k] = live ? s.y : -1.0f;
    }
}

} // namespace

extern "C" void kernel_launch(void* const* d_in, const int* in_sizes, int n_in,
                              void* d_out, int out_size, void* d_ws, size_t ws_size,
                              hipStream_t stream) {
    (void)in_sizes; (void)n_in; (void)out_size;
    const float* in_t   = (const float*)d_in[0];
    const int*   in_sid = (const int*)d_in[1];
    const float* wff    = (const float*)d_in[2];
    const float* wrec   = (const float*)d_in[3];

    float* out_t  = (float*)d_out;
    float* out_id = (float*)d_out + BATCH * MOUT;

    float* wffT = (float*)d_ws;
    const size_t need = (size_t)(NSYN * NNEUR) * sizeof(float);
    const int use_t = (ws_size >= need) ? 1 : 0;

    if (use_t) {
        transpose_wff_kernel<<<(NSYN * NNEUR) / 256, 256, 0, stream>>>(wff, wffT);
    }
    lif_event_kernel<<<BATCH, 64, LDS_TOTAL, stream>>>(in_t, in_sid, wff, wffT, wrec,
                                                       use_t, out_t, out_id);
}

// Round 11
// 179.722 us; speedup vs baseline: 1.2487x; 1.2487x over previous
//
#include <hip/hip_runtime.h>

namespace {

constexpr int BATCH = 256;
constexpr int S_IN  = 256;
constexpr int NNEUR = 128;
constexpr int NSYN  = 256;
constexpr int MOUT  = 256;
constexpr int WSTR  = 130;            // padded LDS stride for WrecT rows
constexpr float NO_SPIKE_T = 1.0e30f; // finite sentinel (ref holds inf; inf-inf=nan fails)
constexpr float K1  = 0.72134752044448170f;  // log2(e)/2  : exp(t/2) = 2^(K1*t)
constexpr float NL2 = -1.3862943611198906f;  // -2*ln2     : t = NL2*log2(z)
constexpr float ZEPS = (float)(1.0 - 1e-6);
constexpr float Z20F = 4.5399929762484854e-05f;  // e^-10  (t=20 bound in z-space)

// dynamic LDS layout (bytes)
constexpr int LDS_WREC  = NNEUR * WSTR * 4;        // 66560
constexpr int LDS_EV    = LDS_WREC;                // float4 ev[264]: {sid_bits, z_in, e, e^2}
constexpr int LDS_SPK   = LDS_EV + 264 * 16;       // float2 spk[256]: {t_spk, (float)jn}
constexpr int LDS_LT    = LDS_SPK + 256 * 8;       // lt[256] f32 (sort scratch)
constexpr int LDS_TOTAL = LDS_LT + 1024;           // 73856

__device__ __forceinline__ float hw_exp2(float x) { return __builtin_amdgcn_exp2f(x); }
__device__ __forceinline__ float hw_log2(float x) { return __builtin_amdgcn_logf(x); }
__device__ __forceinline__ float hw_rcp(float x)  { return __builtin_amdgcn_rcpf(x); }

__global__ void transpose_wff_kernel(const float* __restrict__ wff,
                                     float* __restrict__ wffT) {
    int i = blockIdx.x * blockDim.x + threadIdx.x;   // 32768 threads
    int s = i >> 7;
    int n = i & (NNEUR - 1);
    wffT[i] = wff[n * NSYN + s];
}

template <int CTRL>
__device__ __forceinline__ int dpp_imax(int v) {
    int t = __builtin_amdgcn_update_dpp(v, v, CTRL, 0xf, 0xf, false);
    return (t > v) ? t : v;
}

__device__ __forceinline__ int argmax_key(float zc, int idxl) {
    // truncated z (top 25 bits) | (127-idx): int-max == max z, ties -> lowest idx
    int key = (__builtin_bit_cast(int, zc) & ~127) | (127 - idxl);
    key = dpp_imax<0x111>(key);   // row_shr:1
    key = dpp_imax<0x112>(key);   // row_shr:2
    key = dpp_imax<0x114>(key);   // row_shr:4
    key = dpp_imax<0x118>(key);   // row_shr:8
    key = dpp_imax<0x142>(key);   // row_bcast:15
    key = dpp_imax<0x143>(key);   // row_bcast:31
    return key;
}

// z-space candidate: largest valid root z of A z - B z^2 = 1 in (1e-12, zlim).
// z2 >= z1; t = -2 ln z decreasing in z, so max valid z == min t. Invalid -> 0.
__device__ __forceinline__ float cand_z(float A, float B, float zlim) {
    float disc = __builtin_fmaf(A, A, -4.0f * B);
    float r2B  = hw_rcp(B + B);
    float sq   = __fsqrt_rn(disc);          // nan if disc<0 -> masked below
    float z2 = (A + sq) * r2B;
    float z1 = (A - sq) * r2B;
    bool okd = (disc > 0.0f) & (B > 1e-12f);
    bool v2 = okd & (z2 > 1e-12f) & (z2 < zlim);
    bool v1 = okd & (z1 > 1e-12f) & (z1 < zlim);
    return v2 ? z2 : (v1 ? z1 : 0.0f);
}

__global__ __launch_bounds__(64, 1) void lif_event_kernel(
    const float* __restrict__ in_t,
    const int*   __restrict__ in_sid,
    const float* __restrict__ wff,    // (N,NSYN) original, fallback
    const float* __restrict__ wffT,   // (NSYN,N) transposed, preferred
    const float* __restrict__ wrec,   // (N,N) original; staged->LDS transposed
    int use_t,
    float* __restrict__ out_t,
    float* __restrict__ out_id)
{
    extern __shared__ char smem[];
    float*  wrecL = (float*)smem;                 // [j*WSTR + n] = wrec[n][j]
    float4* evL   = (float4*)(smem + LDS_EV);
    float2* spkL  = (float2*)(smem + LDS_SPK);
    float*  lt    = (float*)(smem + LDS_LT);

    const int b = blockIdx.x;
    const int lane = threadIdx.x;

    // ---- stage WrecT into LDS ----
    const float4* wrec4 = (const float4*)wrec;
    for (int i = lane; i < NNEUR * NNEUR / 4; i += 64) {
        float4 v = wrec4[i];
        int n  = i >> 5;
        int c0 = (i & 31) * 4;
        wrecL[(c0 + 0) * WSTR + n] = v.x;
        wrecL[(c0 + 1) * WSTR + n] = v.y;
        wrecL[(c0 + 2) * WSTR + n] = v.z;
        wrecL[(c0 + 3) * WSTR + n] = v.w;
    }

    // ---- load events; stable rank sort; precompute per-event exponentials ----
    float myt[4]; int mys[4];
    for (int q = 0; q < 4; ++q) {
        int k = lane + 64 * q;
        myt[q] = in_t[b * S_IN + k];
        mys[q] = in_sid[b * S_IN + k];
        lt[k] = myt[q];
    }
    __syncthreads();
    int rk[4] = {0, 0, 0, 0};
    for (int j = 0; j < S_IN; ++j) {
        float tj = lt[j];
        #pragma unroll
        for (int q = 0; q < 4; ++q)
            rk[q] += (tj < myt[q] || (tj == myt[q] && j < lane + 64 * q)) ? 1 : 0;
    }
    for (int q = 0; q < 4; ++q) {
        float t = myt[q];
        float zi = hw_exp2(-K1 * t);    // z_in = exp(-t/2)
        float e  = hw_exp2(K1 * t);     // exp(t/2)
        evL[rk[q]] = make_float4(__builtin_bit_cast(float, mys[q]), zi, e, e * e);
    }
    if (lane < 8) evL[S_IN + lane] = make_float4(0.0f, 0.0f, 1.0f, 1.0f);  // pad: t=inf -> z=0
    __syncthreads();

    const int n0 = lane * 2;
    const int n1 = n0 + 1;

    float A0 = 0.f, A1 = 0.f, B0 = 0.f, B1 = 0.f;
    int ptr = 0, cnt = 0;
    float zlim = ZEPS;   // z_cur = 1

    // ---- event slots A..D (depth 4); weights prefetched per slot ----
    float4 evA = evL[0], evB = evL[1], evC = evL[2], evD = evL[3];
    float2 wA, wB, wC, wD;
    {
        int s0 = __builtin_bit_cast(int, evA.x);
        int s1 = __builtin_bit_cast(int, evB.x);
        int s2 = __builtin_bit_cast(int, evC.x);
        int s3 = __builtin_bit_cast(int, evD.x);
        if (use_t) {
            wA = *(const float2*)&wffT[s0 * NNEUR + n0];
            wB = *(const float2*)&wffT[s1 * NNEUR + n0];
            wC = *(const float2*)&wffT[s2 * NNEUR + n0];
            wD = *(const float2*)&wffT[s3 * NNEUR + n0];
        } else {
            wA = make_float2(wff[n0 * NSYN + s0], wff[n1 * NSYN + s0]);
            wB = make_float2(wff[n0 * NSYN + s1], wff[n1 * NSYN + s1]);
            wC = make_float2(wff[n0 * NSYN + s2], wff[n1 * NSYN + s2]);
            wD = make_float2(wff[n0 * NSYN + s3], wff[n1 * NSYN + s3]);
        }
    }

    // ================= PHASE 1: input events remain =================
    while (ptr < S_IN && cnt < MOUT) {
        // current-state candidates
        const float zb0 = cand_z(A0, B0, zlim);
        const float zb1 = cand_z(A1, B1, zlim);
        const float zc = fmaxf(zb0, zb1);
        const int idxl = (zb1 > zb0) ? n1 : n0;

        // speculative post-consume-A state (sequential FMAs = ref rounding)
        const float A0p = __builtin_fmaf(wA.x, evA.z, A0);
        const float A1p = __builtin_fmaf(wA.y, evA.z, A1);
        const float B0p = __builtin_fmaf(wA.x, evA.w, B0);
        const float B1p = __builtin_fmaf(wA.y, evA.w, B1);
        const float zlimA = ZEPS * evA.y;
        const float zb0p = cand_z(A0p, B0p, zlimA);
        const float zb1p = cand_z(A1p, B1p, zlimA);
        const float zcp = fmaxf(zb0p, zb1p);

        // speculative argmax (consumed only on emit)
        const int key = argmax_key(zc, idxl);

        const bool cross  = (zc  > evA.y) & (zc  > Z20F);
        const bool crossp = (zcp > evB.y) & (zcp > Z20F);
        const unsigned long long m  = __ballot(cross);
        const unsigned long long mp = __ballot(crossp);

        if (m != 0ull) {
            // ---- emit from current state ----
            const int key63 = __builtin_amdgcn_readlane(key, 63);
            const int jn = 127 - (key63 & 127);
            const float zmax = __builtin_bit_cast(float, key63 & ~127);
            const float2 wr = *(const float2*)&wrecL[jn * WSTR + n0];
            const float em = hw_rcp(zmax);
            const float es = em * em;
            const float r0 = (n0 == jn) ? 1.0f : 0.0f;
            const float r1 = (n1 == jn) ? 1.0f : 0.0f;
            A0 = __builtin_fmaf(wr.x - r0, em, A0);
            A1 = __builtin_fmaf(wr.y - r1, em, A1);
            B0 = __builtin_fmaf(wr.x, es, B0);
            B1 = __builtin_fmaf(wr.y, es, B1);
            zlim = ZEPS * zmax;
            if (lane == 0)
                spkL[cnt] = make_float2(NL2 * hw_log2(zmax), (float)jn);
            ++cnt;
        } else {
            // ---- consume A (commit speculative state) ----
            A0 = A0p; A1 = A1p; B0 = B0p; B1 = B1p;
            if (mp == 0ull && ptr + 1 < S_IN) {
                // ---- consume B too (double) ----
                A0 = __builtin_fmaf(wB.x, evB.z, A0);
                A1 = __builtin_fmaf(wB.y, evB.z, A1);
                B0 = __builtin_fmaf(wB.x, evB.w, B0);
                B1 = __builtin_fmaf(wB.y, evB.w, B1);
                zlim = ZEPS * evB.y;
                ptr += 2;
                evA = evC; evB = evD; wA = wC; wB = wD;
                evC = evL[ptr + 2]; evD = evL[ptr + 3];
                const int s2 = __builtin_bit_cast(int, evC.x);
                const int s3 = __builtin_bit_cast(int, evD.x);
                if (use_t) {
                    wC = *(const float2*)&wffT[s2 * NNEUR + n0];
                    wD = *(const float2*)&wffT[s3 * NNEUR + n0];
                } else {
                    wC = make_float2(wff[n0 * NSYN + s2], wff[n1 * NSYN + s2]);
                    wD = make_float2(wff[n0 * NSYN + s3], wff[n1 * NSYN + s3]);
                }
            } else {
                zlim = zlimA;
                ptr += 1;
                evA = evB; evB = evC; evC = evD;
                wA = wB; wB = wC; wC = wD;
                evD = evL[ptr + 3];
                const int s3 = __builtin_bit_cast(int, evD.x);
                if (use_t) {
                    wD = *(const float2*)&wffT[s3 * NNEUR + n0];
                } else {
                    wD = make_float2(wff[n0 * NSYN + s3], wff[n1 * NSYN + s3]);
                }
            }
        }
    }

    // ================= PHASE 2: pure emit drain (LDS-only) =================
    for (int it2 = 0; it2 < MOUT && cnt < MOUT; ++it2) {
        const float zb0 = cand_z(A0, B0, zlim);
        const float zb1 = cand_z(A1, B1, zlim);
        const float zc = fmaxf(zb0, zb1);
        const int idxl = (zb1 > zb0) ? n1 : n0;
        const int key = argmax_key(zc, idxl);          // overlaps ballot/branch
        const unsigned long long m = __ballot(zc > Z20F);
        if (m == 0ull) break;                          // frozen
        const int key63 = __builtin_amdgcn_readlane(key, 63);
        const int jn = 127 - (key63 & 127);
        const float zmax = __builtin_bit_cast(float, key63 & ~127);
        const float2 wr = *(const float2*)&wrecL[jn * WSTR + n0];
        const float em = hw_rcp(zmax);
        const float es = em * em;
        const float r0 = (n0 == jn) ? 1.0f : 0.0f;
        const float r1 = (n1 == jn) ? 1.0f : 0.0f;
        A0 = __builtin_fmaf(wr.x - r0, em, A0);
        A1 = __builtin_fmaf(wr.y - r1, em, A1);
        B0 = __builtin_fmaf(wr.x, es, B0);
        B1 = __builtin_fmaf(wr.y, es, B1);
        zlim = ZEPS * zmax;
        if (lane == 0)
            spkL[cnt] = make_float2(NL2 * hw_log2(zmax), (float)jn);
        ++cnt;
    }

    // ---- flush spikes + fills from LDS to global (coalesced, once) ----
    __syncthreads();
    for (int k = lane; k < MOUT; k += 64) {
        float2 s = spkL[k];
        bool live = (k < cnt);
        out_t[b * MOUT + k]  = live ? s.x : NO_SPIKE_T;
        out_id[b * MOUT + k] = live ? s.y : -1.0f;
    }
}

} // namespace

extern "C" void kernel_launch(void* const* d_in, const int* in_sizes, int n_in,
                              void* d_out, int out_size, void* d_ws, size_t ws_size,
                              hipStream_t stream) {
    (void)in_sizes; (void)n_in; (void)out_size;
    const float* in_t   = (const float*)d_in[0];
    const int*   in_sid = (const int*)d_in[1];
    const float* wff    = (const float*)d_in[2];
    const float* wrec   = (const float*)d_in[3];

    float* out_t  = (float*)d_out;
    float* out_id = (float*)d_out + BATCH * MOUT;

    float* wffT = (float*)d_ws;
    const size_t need = (size_t)(NSYN * NNEUR) * sizeof(float);
    const int use_t = (ws_size >= need) ? 1 : 0;

    if (use_t) {
        transpose_wff_kernel<<<(NSYN * NNEUR) / 256, 256, 0, stream>>>(wff, wffT);
    }
    lif_event_kernel<<<BATCH, 64, LDS_TOTAL, stream>>>(in_t, in_sid, wff, wffT, wrec,
                                                       use_t, out_t, out_id);
}

// Round 12
// 173.651 us; speedup vs baseline: 1.2924x; 1.0350x over previous
//
#include <hip/hip_runtime.h>

namespace {

constexpr int BATCH = 256;
constexpr int S_IN  = 256;
constexpr int NNEUR = 128;
constexpr int NSYN  = 256;
constexpr int MOUT  = 256;
constexpr int WSTR  = 130;            // padded LDS stride for WrecT rows
constexpr float NO_SPIKE_T = 1.0e30f; // finite sentinel (ref holds inf; inf-inf=nan fails)
constexpr float K1  = 0.72134752044448170f;  // log2(e)/2  : exp(t/2) = 2^(K1*t)
constexpr float NL2 = -1.3862943611198906f;  // -2*ln2     : t = NL2*log2(z)
constexpr float ZEPS = (float)(1.0 - 1e-6);
constexpr float Z20F = 4.5399929762484854e-05f;  // e^-10  (t=20 bound in z-space)

// dynamic LDS layout (bytes)
constexpr int LDS_WREC  = NNEUR * WSTR * 4;        // 66560
constexpr int LDS_EV    = LDS_WREC;                // float4 ev[264]: {sid_bits, z_in, e, e^2}
constexpr int LDS_SPK   = LDS_EV + 264 * 16;       // float2 spk[256]: {t_spk, (float)jn}
constexpr int LDS_LT    = LDS_SPK + 256 * 8;       // lt[256] f32 (sort scratch)
constexpr int LDS_TOTAL = LDS_LT + 1024;           // 73856

__device__ __forceinline__ float hw_exp2(float x) { return __builtin_amdgcn_exp2f(x); }
__device__ __forceinline__ float hw_log2(float x) { return __builtin_amdgcn_logf(x); }
__device__ __forceinline__ float hw_rcp(float x)  { return __builtin_amdgcn_rcpf(x); }

__global__ void transpose_wff_kernel(const float* __restrict__ wff,
                                     float* __restrict__ wffT) {
    int i = blockIdx.x * blockDim.x + threadIdx.x;   // 32768 threads
    int s = i >> 7;
    int n = i & (NNEUR - 1);
    wffT[i] = wff[n * NSYN + s];
}

template <int CTRL>
__device__ __forceinline__ int dpp_imax(int v) {
    int t = __builtin_amdgcn_update_dpp(v, v, CTRL, 0xf, 0xf, false);
    return (t > v) ? t : v;
}

__device__ __forceinline__ int argmax_key(float zc, int idxl) {
    // truncated z (top 25 bits) | (127-idx): int-max == max z, ties -> lowest idx
    int key = (__builtin_bit_cast(int, zc) & ~127) | (127 - idxl);
    key = dpp_imax<0x111>(key);   // row_shr:1
    key = dpp_imax<0x112>(key);   // row_shr:2
    key = dpp_imax<0x114>(key);   // row_shr:4
    key = dpp_imax<0x118>(key);   // row_shr:8
    key = dpp_imax<0x142>(key);   // row_bcast:15
    key = dpp_imax<0x143>(key);   // row_bcast:31
    return key;
}

// z-space candidate: largest valid root z of A z - B z^2 = 1 in (1e-12, zlim).
// z2 >= z1; t = -2 ln z decreasing in z, so max valid z == min t. Invalid -> 0.
__device__ __forceinline__ float cand_z(float A, float B, float zlim) {
    float disc = __builtin_fmaf(A, A, -4.0f * B);
    float r2B  = hw_rcp(B + B);
    float sq   = __fsqrt_rn(disc);          // nan if disc<0 -> masked below
    float z2 = (A + sq) * r2B;
    float z1 = (A - sq) * r2B;
    bool okd = (disc > 0.0f) & (B > 1e-12f);
    bool v2 = okd & (z2 > 1e-12f) & (z2 < zlim);
    bool v1 = okd & (z1 > 1e-12f) & (z1 < zlim);
    return v2 ? z2 : (v1 ? z1 : 0.0f);
}

__global__ __launch_bounds__(64, 1) void lif_event_kernel(
    const float* __restrict__ in_t,
    const int*   __restrict__ in_sid,
    const float* __restrict__ wff,    // (N,NSYN) original, fallback
    const float* __restrict__ wffT,   // (NSYN,N) transposed, preferred
    const float* __restrict__ wrec,   // (N,N) original; staged->LDS transposed
    int use_t,
    float* __restrict__ out_t,
    float* __restrict__ out_id)
{
    extern __shared__ char smem[];
    float*  wrecL = (float*)smem;                 // [j*WSTR + n] = wrec[n][j]
    float4* evL   = (float4*)(smem + LDS_EV);
    float2* spkL  = (float2*)(smem + LDS_SPK);
    float*  lt    = (float*)(smem + LDS_LT);

    const int b = blockIdx.x;
    const int lane = threadIdx.x;

    // ---- stage WrecT into LDS ----
    const float4* wrec4 = (const float4*)wrec;
    for (int i = lane; i < NNEUR * NNEUR / 4; i += 64) {
        float4 v = wrec4[i];
        int n  = i >> 5;
        int c0 = (i & 31) * 4;
        wrecL[(c0 + 0) * WSTR + n] = v.x;
        wrecL[(c0 + 1) * WSTR + n] = v.y;
        wrecL[(c0 + 2) * WSTR + n] = v.z;
        wrecL[(c0 + 3) * WSTR + n] = v.w;
    }

    // ---- load events; stable rank sort; precompute per-event exponentials ----
    float myt[4]; int mys[4];
    for (int q = 0; q < 4; ++q) {
        int k = lane + 64 * q;
        myt[q] = in_t[b * S_IN + k];
        mys[q] = in_sid[b * S_IN + k];
        lt[k] = myt[q];
    }
    __syncthreads();
    int rk[4] = {0, 0, 0, 0};
    for (int j = 0; j < S_IN; ++j) {
        float tj = lt[j];
        #pragma unroll
        for (int q = 0; q < 4; ++q)
            rk[q] += (tj < myt[q] || (tj == myt[q] && j < lane + 64 * q)) ? 1 : 0;
    }
    for (int q = 0; q < 4; ++q) {
        float t = myt[q];
        float zi = hw_exp2(-K1 * t);    // z_in = exp(-t/2)
        float e  = hw_exp2(K1 * t);     // exp(t/2)
        evL[rk[q]] = make_float4(__builtin_bit_cast(float, mys[q]), zi, e, e * e);
    }
    if (lane < 8) evL[S_IN + lane] = make_float4(0.0f, 0.0f, 1.0f, 1.0f);  // pad: t=inf -> z=0
    __syncthreads();

    const int n0 = lane * 2;
    const int n1 = n0 + 1;
    const int KZ20 = __builtin_bit_cast(int, Z20F) & ~127;

    float A0 = 0.f, A1 = 0.f, B0 = 0.f, B1 = 0.f;
    int ptr = 0, cnt = 0;
    float zlim = ZEPS;   // z_cur = 1

#define LOADW(dst, sid_)                                                     \
    do {                                                                     \
        const int s_ = (sid_);                                               \
        if (use_t) dst = *(const float2*)&wffT[s_ * NNEUR + n0];             \
        else       dst = make_float2(wff[n0 * NSYN + s_], wff[n1 * NSYN + s_]); \
    } while (0)

    // ---- event slots A..D = events ptr..ptr+3, weights prefetched ----
    float4 evA = evL[0], evB = evL[1], evC = evL[2], evD = evL[3];
    float2 wA, wB, wC, wD;
    LOADW(wA, __builtin_bit_cast(int, evA.x));
    LOADW(wB, __builtin_bit_cast(int, evB.x));
    LOADW(wC, __builtin_bit_cast(int, evC.x));
    LOADW(wD, __builtin_bit_cast(int, evD.x));

    // ================= PHASE 1: quad-consume =================
    while (ptr + 4 <= S_IN && cnt < MOUT) {
        // current-state candidates (+ speculative reduce)
        const float zb0 = cand_z(A0, B0, zlim);
        const float zb1 = cand_z(A1, B1, zlim);
        const float zc = fmaxf(zb0, zb1);
        const int idxl = (zb1 > zb0) ? n1 : n0;
        const int key = argmax_key(zc, idxl);

        // speculative post-consume states S1..S3 (sequential FMA = ref rounding)
        const float A0p = __builtin_fmaf(wA.x, evA.z, A0);
        const float A1p = __builtin_fmaf(wA.y, evA.z, A1);
        const float B0p = __builtin_fmaf(wA.x, evA.w, B0);
        const float B1p = __builtin_fmaf(wA.y, evA.w, B1);
        const float zl1 = ZEPS * evA.y;
        const float zc1 = fmaxf(cand_z(A0p, B0p, zl1), cand_z(A1p, B1p, zl1));

        const float A0q = __builtin_fmaf(wB.x, evB.z, A0p);
        const float A1q = __builtin_fmaf(wB.y, evB.z, A1p);
        const float B0q = __builtin_fmaf(wB.x, evB.w, B0p);
        const float B1q = __builtin_fmaf(wB.y, evB.w, B1p);
        const float zl2 = ZEPS * evB.y;
        const float zc2 = fmaxf(cand_z(A0q, B0q, zl2), cand_z(A1q, B1q, zl2));

        const float A0r = __builtin_fmaf(wC.x, evC.z, A0q);
        const float A1r = __builtin_fmaf(wC.y, evC.z, A1q);
        const float B0r = __builtin_fmaf(wC.x, evC.w, B0q);
        const float B1r = __builtin_fmaf(wC.y, evC.w, B1q);
        const float zl3 = ZEPS * evC.y;
        const float zc3 = fmaxf(cand_z(A0r, B0r, zl3), cand_z(A1r, B1r, zl3));

        const unsigned long long m0 = __ballot((zc  > evA.y) & (zc  > Z20F));
        const unsigned long long m1 = __ballot((zc1 > evB.y) & (zc1 > Z20F));
        const unsigned long long m2 = __ballot((zc2 > evC.y) & (zc2 > Z20F));
        const unsigned long long m3 = __ballot((zc3 > evD.y) & (zc3 > Z20F));

        if (m0 != 0ull) {
            // ---- emit from current state ----
            const int key63 = __builtin_amdgcn_readlane(key, 63);
            const int jn = 127 - (key63 & 127);
            const float zmax = __builtin_bit_cast(float, key63 & ~127);
            const float2 wr = *(const float2*)&wrecL[jn * WSTR + n0];
            const float em = hw_rcp(zmax);
            const float es = em * em;
            const float r0 = (n0 == jn) ? 1.0f : 0.0f;
            const float r1 = (n1 == jn) ? 1.0f : 0.0f;
            A0 = __builtin_fmaf(wr.x - r0, em, A0);
            A1 = __builtin_fmaf(wr.y - r1, em, A1);
            B0 = __builtin_fmaf(wr.x, es, B0);
            B1 = __builtin_fmaf(wr.y, es, B1);
            zlim = ZEPS * zmax;
            if (lane == 0)
                spkL[cnt] = make_float2(NL2 * hw_log2(zmax), (float)jn);
            ++cnt;
        } else if (m1 != 0ull) {
            // commit 1 event
            A0 = A0p; A1 = A1p; B0 = B0p; B1 = B1p; zlim = zl1; ptr += 1;
            evA = evB; evB = evC; evC = evD; wA = wB; wB = wC; wC = wD;
            evD = evL[ptr + 3];
            LOADW(wD, __builtin_bit_cast(int, evD.x));
        } else if (m2 != 0ull) {
            // commit 2 events
            A0 = A0q; A1 = A1q; B0 = B0q; B1 = B1q; zlim = zl2; ptr += 2;
            evA = evC; evB = evD; wA = wC; wB = wD;
            evC = evL[ptr + 2]; evD = evL[ptr + 3];
            LOADW(wC, __builtin_bit_cast(int, evC.x));
            LOADW(wD, __builtin_bit_cast(int, evD.x));
        } else if (m3 != 0ull) {
            // commit 3 events
            A0 = A0r; A1 = A1r; B0 = B0r; B1 = B1r; zlim = zl3; ptr += 3;
            evA = evD; wA = wD;
            evB = evL[ptr + 1]; evC = evL[ptr + 2]; evD = evL[ptr + 3];
            LOADW(wB, __builtin_bit_cast(int, evB.x));
            LOADW(wC, __builtin_bit_cast(int, evC.x));
            LOADW(wD, __builtin_bit_cast(int, evD.x));
        } else {
            // commit 4 events
            A0 = __builtin_fmaf(wD.x, evD.z, A0r);
            A1 = __builtin_fmaf(wD.y, evD.z, A1r);
            B0 = __builtin_fmaf(wD.x, evD.w, B0r);
            B1 = __builtin_fmaf(wD.y, evD.w, B1r);
            zlim = ZEPS * evD.y; ptr += 4;
            evA = evL[ptr + 0]; evB = evL[ptr + 1];
            evC = evL[ptr + 2]; evD = evL[ptr + 3];
            LOADW(wA, __builtin_bit_cast(int, evA.x));
            LOADW(wB, __builtin_bit_cast(int, evB.x));
            LOADW(wC, __builtin_bit_cast(int, evC.x));
            LOADW(wD, __builtin_bit_cast(int, evD.x));
        }
    }

    // ---- tail: single-step until inputs exhausted ----
    while (ptr < S_IN && cnt < MOUT) {
        const float zb0 = cand_z(A0, B0, zlim);
        const float zb1 = cand_z(A1, B1, zlim);
        const float zc = fmaxf(zb0, zb1);
        const int idxl = (zb1 > zb0) ? n1 : n0;
        const int key = argmax_key(zc, idxl);
        const unsigned long long m = __ballot((zc > evA.y) & (zc > Z20F));
        if (m != 0ull) {
            const int key63 = __builtin_amdgcn_readlane(key, 63);
            const int jn = 127 - (key63 & 127);
            const float zmax = __builtin_bit_cast(float, key63 & ~127);
            const float2 wr = *(const float2*)&wrecL[jn * WSTR + n0];
            const float em = hw_rcp(zmax);
            const float es = em * em;
            const float r0 = (n0 == jn) ? 1.0f : 0.0f;
            const float r1 = (n1 == jn) ? 1.0f : 0.0f;
            A0 = __builtin_fmaf(wr.x - r0, em, A0);
            A1 = __builtin_fmaf(wr.y - r1, em, A1);
            B0 = __builtin_fmaf(wr.x, es, B0);
            B1 = __builtin_fmaf(wr.y, es, B1);
            zlim = ZEPS * zmax;
            if (lane == 0)
                spkL[cnt] = make_float2(NL2 * hw_log2(zmax), (float)jn);
            ++cnt;
        } else {
            A0 = __builtin_fmaf(wA.x, evA.z, A0);
            A1 = __builtin_fmaf(wA.y, evA.z, A1);
            B0 = __builtin_fmaf(wA.x, evA.w, B0);
            B1 = __builtin_fmaf(wA.y, evA.w, B1);
            zlim = ZEPS * evA.y;
            ++ptr;
            evA = evB; evB = evC; evC = evD; wA = wB; wB = wC; wC = wD;
            evD = evL[ptr + 3];
            LOADW(wD, __builtin_bit_cast(int, evD.x));
        }
    }

    // ================= PHASE 2: pure emit drain (LDS-only, x2 unrolled) =================
    while (cnt < MOUT) {
        {
            const float zb0 = cand_z(A0, B0, zlim);
            const float zb1 = cand_z(A1, B1, zlim);
            const float zc = fmaxf(zb0, zb1);
            const int idxl = (zb1 > zb0) ? n1 : n0;
            const int key = argmax_key(zc, idxl);
            const int key63 = __builtin_amdgcn_readlane(key, 63);
            if ((key63 & ~127) <= KZ20) { cnt = -cnt; break; }   // frozen (flag via sign)
            const int jn = 127 - (key63 & 127);
            const float zmax = __builtin_bit_cast(float, key63 & ~127);
            const float2 wr = *(const float2*)&wrecL[jn * WSTR + n0];
            const float em = hw_rcp(zmax);
            const float es = em * em;
            const float r0 = (n0 == jn) ? 1.0f : 0.0f;
            const float r1 = (n1 == jn) ? 1.0f : 0.0f;
            A0 = __builtin_fmaf(wr.x - r0, em, A0);
            A1 = __builtin_fmaf(wr.y - r1, em, A1);
            B0 = __builtin_fmaf(wr.x, es, B0);
            B1 = __builtin_fmaf(wr.y, es, B1);
            zlim = ZEPS * zmax;
            if (lane == 0)
                spkL[cnt] = make_float2(NL2 * hw_log2(zmax), (float)jn);
            ++cnt;
        }
        if (cnt >= MOUT) break;
        {
            const float zb0 = cand_z(A0, B0, zlim);
            const float zb1 = cand_z(A1, B1, zlim);
            const float zc = fmaxf(zb0, zb1);
            const int idxl = (zb1 > zb0) ? n1 : n0;
            const int key = argmax_key(zc, idxl);
            const int key63 = __builtin_amdgcn_readlane(key, 63);
            if ((key63 & ~127) <= KZ20) { cnt = -cnt; break; }
            const int jn = 127 - (key63 & 127);
            const float zmax = __builtin_bit_cast(float, key63 & ~127);
            const float2 wr = *(const float2*)&wrecL[jn * WSTR + n0];
            const float em = hw_rcp(zmax);
            const float es = em * em;
            const float r0 = (n0 == jn) ? 1.0f : 0.0f;
            const float r1 = (n1 == jn) ? 1.0f : 0.0f;
            A0 = __builtin_fmaf(wr.x - r0, em, A0);
            A1 = __builtin_fmaf(wr.y - r1, em, A1);
            B0 = __builtin_fmaf(wr.x, es, B0);
            B1 = __builtin_fmaf(wr.y, es, B1);
            zlim = ZEPS * zmax;
            if (lane == 0)
                spkL[cnt] = make_float2(NL2 * hw_log2(zmax), (float)jn);
            ++cnt;
        }
    }
    if (cnt < 0) cnt = -cnt;   // unflag frozen marker
#undef LOADW

    // ---- flush spikes + fills from LDS to global (coalesced, once) ----
    __syncthreads();
    for (int k = lane; k < MOUT; k += 64) {
        float2 s = spkL[k];
        bool live = (k < cnt);
        out_t[b * MOUT + k]  = live ? s.x : NO_SPIKE_T;
        out_id[b * MOUT + k] = live ? s.y : -1.0f;
    }
}

} // namespace

extern "C" void kernel_launch(void* const* d_in, const int* in_sizes, int n_in,
                              void* d_out, int out_size, void* d_ws, size_t ws_size,
                              hipStream_t stream) {
    (void)in_sizes; (void)n_in; (void)out_size;
    const float* in_t   = (const float*)d_in[0];
    const int*   in_sid = (const int*)d_in[1];
    const float* wff    = (const float*)d_in[2];
    const float* wrec   = (const float*)d_in[3];

    float* out_t  = (float*)d_out;
    float* out_id = (float*)d_out + BATCH * MOUT;

    float* wffT = (float*)d_ws;
    const size_t need = (size_t)(NSYN * NNEUR) * sizeof(float);
    const int use_t = (ws_size >= need) ? 1 : 0;

    if (use_t) {
        transpose_wff_kernel<<<(NSYN * NNEUR) / 256, 256, 0, stream>>>(wff, wffT);
    }
    lif_event_kernel<<<BATCH, 64, LDS_TOTAL, stream>>>(in_t, in_sid, wff, wffT, wrec,
                                                       use_t, out_t, out_id);
}

// Round 13
// 163.514 us; speedup vs baseline: 1.3725x; 1.0620x over previous
//
#include <hip/hip_runtime.h>

namespace {

constexpr int BATCH = 256;
constexpr int S_IN  = 256;
constexpr int NNEUR = 128;
constexpr int NSYN  = 256;
constexpr int MOUT  = 256;
constexpr int WSTR  = 130;            // padded LDS stride for WrecT rows
constexpr float NO_SPIKE_T = 1.0e30f; // finite sentinel (ref holds inf; inf-inf=nan fails)
constexpr float K1  = 0.72134752044448170f;  // log2(e)/2  : exp(t/2) = 2^(K1*t)
constexpr float NL2 = -1.3862943611198906f;  // -2*ln2     : t = NL2*log2(z)
constexpr float ZEPS = (float)(1.0 - 1e-6);
constexpr float Z20F = 4.5399929762484854e-05f;  // e^-10  (t=20 bound in z-space)

// dynamic LDS layout (bytes)
constexpr int LDS_WREC  = NNEUR * WSTR * 4;        // 66560
constexpr int LDS_EV    = LDS_WREC;                // float4 ev[264]: {sid_bits, z_in, e, e^2}
constexpr int LDS_SPK   = LDS_EV + 264 * 16;       // int spk[264]: packed emit keys
constexpr int LDS_LT    = LDS_SPK + 264 * 4;       // lt[256] f32 (sort scratch)
constexpr int LDS_TOTAL = LDS_LT + 1024;           // 72848

__device__ __forceinline__ float hw_exp2(float x) { return __builtin_amdgcn_exp2f(x); }
__device__ __forceinline__ float hw_log2(float x) { return __builtin_amdgcn_logf(x); }
__device__ __forceinline__ float hw_rcp(float x)  { return __builtin_amdgcn_rcpf(x); }

__global__ void transpose_wff_kernel(const float* __restrict__ wff,
                                     float* __restrict__ wffT) {
    int i = blockIdx.x * blockDim.x + threadIdx.x;   // 32768 threads
    int s = i >> 7;
    int n = i & (NNEUR - 1);
    wffT[i] = wff[n * NSYN + s];
}

template <int CTRL>
__device__ __forceinline__ int dpp_imax(int v) {
    int t = __builtin_amdgcn_update_dpp(v, v, CTRL, 0xf, 0xf, false);
    return (t > v) ? t : v;
}

// z-space candidate: largest valid root z of A z - B z^2 = 1 in (1e-12, zlim).
// z2 >= z1; t = -2 ln z decreasing in z, so max valid z == min t. Invalid -> 0.
// nan inputs (post-freeze poison) -> all compares false -> 0.
__device__ __forceinline__ float cand_z(float A, float B, float zlim) {
    float disc = __builtin_fmaf(A, A, -4.0f * B);
    float r2B  = hw_rcp(B + B);
    float sq   = __fsqrt_rn(disc);
    float z2 = (A + sq) * r2B;
    float z1 = (A - sq) * r2B;
    bool okd = (disc > 0.0f) & (B > 1e-12f);
    bool v2 = okd & (z2 > 1e-12f) & (z2 < zlim);
    bool v1 = okd & (z1 > 1e-12f) & (z1 < zlim);
    return v2 ? z2 : (v1 ? z1 : 0.0f);
}

__global__ __launch_bounds__(64, 1) void lif_event_kernel(
    const float* __restrict__ in_t,
    const int*   __restrict__ in_sid,
    const float* __restrict__ wff,    // (N,NSYN) original, fallback
    const float* __restrict__ wffT,   // (NSYN,N) transposed, preferred
    const float* __restrict__ wrec,   // (N,N) original; staged->LDS transposed
    int use_t,
    float* __restrict__ out_t,
    float* __restrict__ out_id)
{
    extern __shared__ char smem[];
    float*  wrecL = (float*)smem;                 // [j*WSTR + n] = wrec[n][j]
    float4* evL   = (float4*)(smem + LDS_EV);
    int*    spkI  = (int*)  (smem + LDS_SPK);
    float*  lt    = (float*)(smem + LDS_LT);

    const int b = blockIdx.x;
    const int lane = threadIdx.x;

    // ---- stage WrecT into LDS ----
    const float4* wrec4 = (const float4*)wrec;
    for (int i = lane; i < NNEUR * NNEUR / 4; i += 64) {
        float4 v = wrec4[i];
        int n  = i >> 5;
        int c0 = (i & 31) * 4;
        wrecL[(c0 + 0) * WSTR + n] = v.x;
        wrecL[(c0 + 1) * WSTR + n] = v.y;
        wrecL[(c0 + 2) * WSTR + n] = v.z;
        wrecL[(c0 + 3) * WSTR + n] = v.w;
    }

    // ---- load events; stable rank sort; precompute per-event exponentials ----
    float myt[4]; int mys[4];
    for (int q = 0; q < 4; ++q) {
        int k = lane + 64 * q;
        myt[q] = in_t[b * S_IN + k];
        mys[q] = in_sid[b * S_IN + k];
        lt[k] = myt[q];
    }
    __syncthreads();
    int rk[4] = {0, 0, 0, 0};
    for (int j = 0; j < S_IN; ++j) {
        float tj = lt[j];
        #pragma unroll
        for (int q = 0; q < 4; ++q)
            rk[q] += (tj < myt[q] || (tj == myt[q] && j < lane + 64 * q)) ? 1 : 0;
    }
    for (int q = 0; q < 4; ++q) {
        float t = myt[q];
        float zi = hw_exp2(-K1 * t);    // z_in = exp(-t/2)
        float e  = hw_exp2(K1 * t);     // exp(t/2)
        evL[rk[q]] = make_float4(__builtin_bit_cast(float, mys[q]), zi, e, e * e);
    }
    if (lane < 8) evL[S_IN + lane] = make_float4(0.0f, 0.0f, 1.0f, 1.0f);  // pad: t=inf -> z=0
    __syncthreads();

    const int n0 = lane * 2;
    const int n1 = n0 + 1;
    const int KZ20 = __builtin_bit_cast(int, Z20F) & ~127;

    float A0 = 0.f, A1 = 0.f, B0 = 0.f, B1 = 0.f;
    int ptr = 0, cnt = 0;
    float zlim = ZEPS;   // z_cur = 1

#define LOADW(dst, sid_)                                                     \
    do {                                                                     \
        const int s_ = (sid_);                                               \
        if (use_t) dst = *(const float2*)&wffT[s_ * NNEUR + n0];             \
        else       dst = make_float2(wff[n0 * NSYN + s_], wff[n1 * NSYN + s_]); \
    } while (0)

// full argmax key reduce: kk (wave-uniform) = max over lanes of
// (zc_bits & ~127) | (127 - idxl);  int-max == max z, ties -> lowest idx
#define REDUCE_KEY(kk, zc, idxl)                                             \
    do {                                                                     \
        int key_ = (__builtin_bit_cast(int, (zc)) & ~127) | (127 - (idxl));  \
        key_ = dpp_imax<0x111>(key_);                                        \
        key_ = dpp_imax<0x112>(key_);                                        \
        key_ = dpp_imax<0x114>(key_);                                        \
        key_ = dpp_imax<0x118>(key_);                                        \
        key_ = dpp_imax<0x142>(key_);                                        \
        key_ = dpp_imax<0x143>(key_);                                        \
        kk = __builtin_amdgcn_readlane(key_, 63);                            \
    } while (0)

// apply emit update from a uniform key kk (branchless)
#define APPLY_EMIT(kk)                                                       \
    do {                                                                     \
        const int jn_ = 127 - ((kk) & 127);                                  \
        const float zmax_ = __builtin_bit_cast(float, (kk) & ~127);          \
        const float2 wr_ = *(const float2*)&wrecL[jn_ * WSTR + n0];          \
        const float em_ = hw_rcp(zmax_);                                     \
        const float es_ = em_ * em_;                                         \
        const float r0_ = (n0 == jn_) ? 1.0f : 0.0f;                         \
        const float r1_ = (n1 == jn_) ? 1.0f : 0.0f;                         \
        A0 = __builtin_fmaf(wr_.x - r0_, em_, A0);                           \
        A1 = __builtin_fmaf(wr_.y - r1_, em_, A1);                           \
        B0 = __builtin_fmaf(wr_.x, es_, B0);                                 \
        B1 = __builtin_fmaf(wr_.y, es_, B1);                                 \
        zlim = ZEPS * zmax_;                                                 \
    } while (0)

    // ---- event slots A..D = events ptr..ptr+3, weights prefetched ----
    float4 evA = evL[0], evB = evL[1], evC = evL[2], evD = evL[3];
    float2 wA, wB, wC, wD;
    LOADW(wA, __builtin_bit_cast(int, evA.x));
    LOADW(wB, __builtin_bit_cast(int, evB.x));
    LOADW(wC, __builtin_bit_cast(int, evC.x));
    LOADW(wD, __builtin_bit_cast(int, evD.x));

    // ================= PHASE 1: quad-consume =================
    while (ptr + 4 <= S_IN && cnt < MOUT) {
        // current-state candidates (+ speculative reduce)
        const float zb0 = cand_z(A0, B0, zlim);
        const float zb1 = cand_z(A1, B1, zlim);
        const float zc = fmaxf(zb0, zb1);
        const int idxl = (zb1 > zb0) ? n1 : n0;
        int key;
        REDUCE_KEY(key, zc, idxl);

        // speculative post-consume states S1..S3 (sequential FMA = ref rounding)
        const float A0p = __builtin_fmaf(wA.x, evA.z, A0);
        const float A1p = __builtin_fmaf(wA.y, evA.z, A1);
        const float B0p = __builtin_fmaf(wA.x, evA.w, B0);
        const float B1p = __builtin_fmaf(wA.y, evA.w, B1);
        const float zl1 = ZEPS * evA.y;
        const float zc1 = fmaxf(cand_z(A0p, B0p, zl1), cand_z(A1p, B1p, zl1));

        const float A0q = __builtin_fmaf(wB.x, evB.z, A0p);
        const float A1q = __builtin_fmaf(wB.y, evB.z, A1p);
        const float B0q = __builtin_fmaf(wB.x, evB.w, B0p);
        const float B1q = __builtin_fmaf(wB.y, evB.w, B1p);
        const float zl2 = ZEPS * evB.y;
        const float zc2 = fmaxf(cand_z(A0q, B0q, zl2), cand_z(A1q, B1q, zl2));

        const float A0r = __builtin_fmaf(wC.x, evC.z, A0q);
        const float A1r = __builtin_fmaf(wC.y, evC.z, A1q);
        const float B0r = __builtin_fmaf(wC.x, evC.w, B0q);
        const float B1r = __builtin_fmaf(wC.y, evC.w, B1q);
        const float zl3 = ZEPS * evC.y;
        const float zc3 = fmaxf(cand_z(A0r, B0r, zl3), cand_z(A1r, B1r, zl3));

        const unsigned long long m0 = __ballot((zc  > evA.y) & (zc  > Z20F));
        const unsigned long long m1 = __ballot((zc1 > evB.y) & (zc1 > Z20F));
        const unsigned long long m2 = __ballot((zc2 > evC.y) & (zc2 > Z20F));
        const unsigned long long m3 = __ballot((zc3 > evD.y) & (zc3 > Z20F));

        if (m0 != 0ull) {
            APPLY_EMIT(key);
            if (lane == 0) spkI[cnt] = key;
            ++cnt;
        } else if (m1 != 0ull) {
            A0 = A0p; A1 = A1p; B0 = B0p; B1 = B1p; zlim = zl1; ptr += 1;
            evA = evB; evB = evC; evC = evD; wA = wB; wB = wC; wC = wD;
            evD = evL[ptr + 3];
            LOADW(wD, __builtin_bit_cast(int, evD.x));
        } else if (m2 != 0ull) {
            A0 = A0q; A1 = A1q; B0 = B0q; B1 = B1q; zlim = zl2; ptr += 2;
            evA = evC; evB = evD; wA = wC; wB = wD;
            evC = evL[ptr + 2]; evD = evL[ptr + 3];
            LOADW(wC, __builtin_bit_cast(int, evC.x));
            LOADW(wD, __builtin_bit_cast(int, evD.x));
        } else if (m3 != 0ull) {
            A0 = A0r; A1 = A1r; B0 = B0r; B1 = B1r; zlim = zl3; ptr += 3;
            evA = evD; wA = wD;
            evB = evL[ptr + 1]; evC = evL[ptr + 2]; evD = evL[ptr + 3];
            LOADW(wB, __builtin_bit_cast(int, evB.x));
            LOADW(wC, __builtin_bit_cast(int, evC.x));
            LOADW(wD, __builtin_bit_cast(int, evD.x));
        } else {
            A0 = __builtin_fmaf(wD.x, evD.z, A0r);
            A1 = __builtin_fmaf(wD.y, evD.z, A1r);
            B0 = __builtin_fmaf(wD.x, evD.w, B0r);
            B1 = __builtin_fmaf(wD.y, evD.w, B1r);
            zlim = ZEPS * evD.y; ptr += 4;
            evA = evL[ptr + 0]; evB = evL[ptr + 1];
            evC = evL[ptr + 2]; evD = evL[ptr + 3];
            LOADW(wA, __builtin_bit_cast(int, evA.x));
            LOADW(wB, __builtin_bit_cast(int, evB.x));
            LOADW(wC, __builtin_bit_cast(int, evC.x));
            LOADW(wD, __builtin_bit_cast(int, evD.x));
        }
    }

    // ---- tail: single-step until inputs exhausted ----
    while (ptr < S_IN && cnt < MOUT) {
        const float zb0 = cand_z(A0, B0, zlim);
        const float zb1 = cand_z(A1, B1, zlim);
        const float zc = fmaxf(zb0, zb1);
        const int idxl = (zb1 > zb0) ? n1 : n0;
        int key;
        REDUCE_KEY(key, zc, idxl);
        const unsigned long long m = __ballot((zc > evA.y) & (zc > Z20F));
        if (m != 0ull) {
            APPLY_EMIT(key);
            if (lane == 0) spkI[cnt] = key;
            ++cnt;
        } else {
            A0 = __builtin_fmaf(wA.x, evA.z, A0);
            A1 = __builtin_fmaf(wA.y, evA.z, A1);
            B0 = __builtin_fmaf(wA.x, evA.w, B0);
            B1 = __builtin_fmaf(wA.y, evA.w, B1);
            zlim = ZEPS * evA.y;
            ++ptr;
            evA = evB; evB = evC; evC = evD; wA = wB; wB = wC; wC = wD;
            evD = evL[ptr + 3];
            LOADW(wD, __builtin_bit_cast(int, evD.x));
        }
    }

    // ===== PHASE 2: pure emit drain — branchless 4-unrolled blocks =====
    // Frozen state self-poisons safely: zc->0, key zmax-bits <= KZ20, and
    // nan/inf states keep producing zc=0. Bogus sub-emits past the freeze
    // point are excluded via cnt += p (first frozen index).
    while (cnt < MOUT) {
        int k0, k1, k2, k3;
        {   // sub-emit 0
            const float zb0 = cand_z(A0, B0, zlim);
            const float zb1 = cand_z(A1, B1, zlim);
            const float zc = fmaxf(zb0, zb1);
            const int idxl = (zb1 > zb0) ? n1 : n0;
            REDUCE_KEY(k0, zc, idxl);
            APPLY_EMIT(k0);
        }
        {   // sub-emit 1
            const float zb0 = cand_z(A0, B0, zlim);
            const float zb1 = cand_z(A1, B1, zlim);
            const float zc = fmaxf(zb0, zb1);
            const int idxl = (zb1 > zb0) ? n1 : n0;
            REDUCE_KEY(k1, zc, idxl);
            APPLY_EMIT(k1);
        }
        {   // sub-emit 2
            const float zb0 = cand_z(A0, B0, zlim);
            const float zb1 = cand_z(A1, B1, zlim);
            const float zc = fmaxf(zb0, zb1);
            const int idxl = (zb1 > zb0) ? n1 : n0;
            REDUCE_KEY(k2, zc, idxl);
            APPLY_EMIT(k2);
        }
        {   // sub-emit 3
            const float zb0 = cand_z(A0, B0, zlim);
            const float zb1 = cand_z(A1, B1, zlim);
            const float zc = fmaxf(zb0, zb1);
            const int idxl = (zb1 > zb0) ? n1 : n0;
            REDUCE_KEY(k3, zc, idxl);
            APPLY_EMIT(k3);
        }
        if (lane == 0) {
            spkI[cnt + 0] = k0; spkI[cnt + 1] = k1;
            spkI[cnt + 2] = k2; spkI[cnt + 3] = k3;
        }
        const bool f0 = (k0 & ~127) <= KZ20;
        const bool f1 = (k1 & ~127) <= KZ20;
        const bool f2 = (k2 & ~127) <= KZ20;
        const bool f3 = (k3 & ~127) <= KZ20;
        const int p = f0 ? 0 : (f1 ? 1 : (f2 ? 2 : (f3 ? 3 : 4)));
        cnt += p;
        if (p < 4) break;
    }
    if (cnt > MOUT) cnt = MOUT;
#undef LOADW
#undef REDUCE_KEY
#undef APPLY_EMIT

    // ---- flush: decode keys -> (t, id), fill the rest (every call) ----
    __syncthreads();
    for (int k = lane; k < MOUT; k += 64) {
        const int kk = spkI[k];
        const bool live = (k < cnt);
        const float zmax = __builtin_bit_cast(float, kk & ~127);
        const float t = NL2 * hw_log2(zmax);
        const float id = (float)(127 - (kk & 127));
        out_t[b * MOUT + k]  = live ? t : NO_SPIKE_T;
        out_id[b * MOUT + k] = live ? id : -1.0f;
    }
}

} // namespace

extern "C" void kernel_launch(void* const* d_in, const int* in_sizes, int n_in,
                              void* d_out, int out_size, void* d_ws, size_t ws_size,
                              hipStream_t stream) {
    (void)in_sizes; (void)n_in; (void)out_size;
    const float* in_t   = (const float*)d_in[0];
    const int*   in_sid = (const int*)d_in[1];
    const float* wff    = (const float*)d_in[2];
    const float* wrec   = (const float*)d_in[3];

    float* out_t  = (float*)d_out;
    float* out_id = (float*)d_out + BATCH * MOUT;

    float* wffT = (float*)d_ws;
    const size_t need = (size_t)(NSYN * NNEUR) * sizeof(float);
    const int use_t = (ws_size >= need) ? 1 : 0;

    if (use_t) {
        transpose_wff_kernel<<<(NSYN * NNEUR) / 256, 256, 0, stream>>>(wff, wffT);
    }
    lif_event_kernel<<<BATCH, 64, LDS_TOTAL, stream>>>(in_t, in_sid, wff, wffT, wrec,
                                                       use_t, out_t, out_id);
}